// Round 4
// baseline (307.408 us; speedup 1.0000x reference)
//
#include <hip/hip_runtime.h>
#include <math.h>

// SparseMOELayer: N=65536 tokens, D=128, E=16 experts, top-3 routing.
// Outputs concat: logits[N*D] | importance_loss[1] | comb[N*E]
#define NTOK 65536
#define DD   128
#define NE   16
#define NK   3
#define TPB  64                    // tokens per block
#define NBLK (NTOK / TPB)          // 1024

#define OUT_LOSS ((size_t)NTOK * DD)
#define OUT_COMB ((size_t)NTOK * DD + 1)

typedef __bf16 bf16x8 __attribute__((ext_vector_type(8)));
typedef float  f32x4  __attribute__((ext_vector_type(4)));

__device__ __forceinline__ double softplus_d(double z) {
    return fmax(z, 0.0) + log1p(exp(-fabs(z)));
}

// ---------------------------------------------------------------------------
// K0: We[e][d][f] fp32 -> WeT[e][f][d] bf16 (B-operand layout: 8 consecutive
// d per n reachable as one 16B load).
// ---------------------------------------------------------------------------
__global__ __launch_bounds__(256) void k_prep(
    const float* __restrict__ We, __bf16* __restrict__ WeT)
{
    __shared__ __bf16 S[DD][DD + 8];
    const int tid = threadIdx.x;
    const int e = blockIdx.x;
    const size_t base = (size_t)e * DD * DD;
    for (int idx = tid; idx < DD * DD; idx += 256) {
        int d = idx >> 7, f = idx & 127;
        S[d][f] = (__bf16)We[base + idx];              // coalesced read
    }
    __syncthreads();
    for (int idx = tid; idx < DD * DD; idx += 256) {
        int f = idx >> 7, d = idx & 127;
        WeT[base + idx] = S[d][f];                     // coalesced write
    }
}

// ---------------------------------------------------------------------------
// K1: gating (R3 structure; pe/pw writes removed — no longer consumed).
// ---------------------------------------------------------------------------
__global__ __launch_bounds__(256, 4) void k_gate(
    const float* __restrict__ x, const float* __restrict__ noise,
    const float* __restrict__ Wg, const float* __restrict__ bg,
    const float* __restrict__ Wn, const float* __restrict__ bn,
    float* __restrict__ out, float* __restrict__ imp_block)
{
    __shared__ float  WgT[NE][DD + 4];
    __shared__ float  WnT[NE][DD + 4];
    __shared__ double gaS[TPB][NE + 1];
    __shared__ double naS[TPB][NE + 1];
    __shared__ float  tk_w[TPB][NK];
    __shared__ int    tk_e[TPB][NK];
    __shared__ float  impS[NE];

    const int tid = threadIdx.x;
    const int n0  = blockIdx.x * TPB;
    const int e   = tid & 15;
    const int tl  = tid >> 4;

    if (tid < NE) impS[tid] = 0.0f;
    for (int i = tid; i < DD * NE; i += 256) {        // transpose-load Wg/Wn
        int d = i >> 4, ee = i & 15;
        WgT[ee][d] = Wg[i];
        WnT[ee][d] = Wn[i];
    }
    __syncthreads();

    // ---- Phase 1: fp64 dots, 8 independent accumulator chains ----
    const float4* wgp = (const float4*)&WgT[e][0];
    const float4* wnp = (const float4*)&WnT[e][0];
    for (int g = 0; g < 4; g++) {
        int t = g * 16 + tl;
        const float4* xp = (const float4*)(x + (size_t)(n0 + t) * DD);
        double g0 = 0, g1 = 0, g2 = 0, g3 = 0;
        double h0 = 0, h1 = 0, h2 = 0, h3 = 0;
        #pragma unroll 4
        for (int q = 0; q < DD / 4; q++) {
            float4 xv = xp[q], wg = wgp[q], wn = wnp[q];
            g0 += (double)xv.x * wg.x; g1 += (double)xv.y * wg.y;
            g2 += (double)xv.z * wg.z; g3 += (double)xv.w * wg.w;
            h0 += (double)xv.x * wn.x; h1 += (double)xv.y * wn.y;
            h2 += (double)xv.z * wn.z; h3 += (double)xv.w * wn.w;
        }
        gaS[t][e] = (g0 + g1) + (g2 + g3);
        naS[t][e] = (h0 + h1) + (h2 + h3);
    }
    __syncthreads();

    // ---- Phase 2: gate = ga + bg + noise * softplus(na + bn) ----
    {
        const double bge = (double)bg[e], bne = (double)bn[e];
        for (int g = 0; g < 4; g++) {
            int t = g * 16 + tl;
            double nz = (double)noise[(size_t)(n0 + t) * NE + e];
            gaS[t][e] = gaS[t][e] + bge + nz * softplus_d(naS[t][e] + bne);
        }
    }
    __syncthreads();

    // ---- Phase 3: top-3 per token ----
    if (tid < TPB) {
        int t = tid;
        double v[NK]; int ix[NK];
        unsigned taken = 0;
        for (int k = 0; k < NK; k++) {
            double best = -INFINITY; int bi = 0;
            for (int j = 0; j < NE; j++) {
                if (!((taken >> j) & 1u)) {
                    double gv = gaS[t][j];
                    if (gv > best) { best = gv; bi = j; }  // strict >: low idx tie
                }
            }
            taken |= 1u << bi;
            v[k] = best; ix[k] = bi;
        }
        double e1 = exp(v[1] - v[0]);
        double e2 = exp(v[2] - v[0]);
        double inv = 1.0 / (1.0 + e1 + e2);
        tk_e[t][0] = ix[0]; tk_e[t][1] = ix[1]; tk_e[t][2] = ix[2];
        tk_w[t][0] = (float)inv;
        tk_w[t][1] = (float)(e1 * inv);
        tk_w[t][2] = (float)(e2 * inv);
    }
    __syncthreads();

    // ---- Phase 4: comb scatter + importance partials ----
    for (int g = 0; g < 4; g++) {
        int t = g * 16 + tl;
        float c = 0.f;
        if (tk_e[t][0] == e) c = tk_w[t][0];
        if (tk_e[t][1] == e) c = tk_w[t][1];
        if (tk_e[t][2] == e) c = tk_w[t][2];
        out[OUT_COMB + (size_t)(n0 + t) * NE + e] = c;
        if (c != 0.f) atomicAdd(&impS[e], c);
    }
    __syncthreads();
    if (tid < NE) imp_block[blockIdx.x * NE + tid] = impS[tid];
}

// ---------------------------------------------------------------------------
// K2: importance loss = (std(imp, ddof=1)/mean)^2.
// ---------------------------------------------------------------------------
__global__ __launch_bounds__(256) void k_loss(
    const float* __restrict__ imp_block, float* __restrict__ out)
{
    __shared__ float red[256];
    __shared__ float impv[NE];
    int tid = threadIdx.x;
    int e = tid & 15, s = tid >> 4;
    float sum = 0.f;
    for (int b = s; b < NBLK; b += 16) sum += imp_block[b * NE + e];
    red[tid] = sum;
    __syncthreads();
    if (tid < NE) {
        float t = 0.f;
        for (int q = 0; q < 16; q++) t += red[q * 16 + tid];
        impv[tid] = t;
    }
    __syncthreads();
    if (tid == 0) {
        double mean = 0.0;
        for (int i = 0; i < NE; i++) mean += (double)impv[i];
        mean /= NE;
        double var = 0.0;
        for (int i = 0; i < NE; i++) {
            double d = (double)impv[i] - mean; var += d * d;
        }
        var /= (NE - 1);
        out[OUT_LOSS] = (float)(var / (mean * mean));
    }
}

// ---------------------------------------------------------------------------
// K3: DENSE expert compute. logits[t] = sum_e comb[t][e]*(x[t]·We[e]+be[e]).
// comb==0 for non-selected experts -> identical to sparse sum, but the loop
// is barrier-free and fully regular:
//  - x tile staged once (bf16, sequential rows -> conflict-free ds_read_b128)
//  - B-frags per expert live in registers (WeT from L2, 512 KB hot)
//  - bias folds in by initializing MFMA acc to be[e][col]
//  - output kept in registers; comb scale from LDS broadcast reads
// Per wave: 16 experts x 4 m-tiles x 4 k-steps x 2 n-tiles = 512 MFMA.
// MFMA 16x16x32 layouts (m89-verified):
//   A: lane l holds A[m=l&15][k=(l>>4)*8+j]; D: col=l&15, row=(l>>4)*4+reg
// ---------------------------------------------------------------------------
__global__ __launch_bounds__(256, 4) void k_expert(
    const float* __restrict__ x, const __bf16* __restrict__ WeT,
    const float* __restrict__ be, const float* __restrict__ comb,
    float* __restrict__ out)
{
    __shared__ __bf16 xsb[TPB][DD + 8];        // 17.4 KB
    __shared__ float  combT[NE][TPB + 4];      // 4.3 KB, [e][t]
    __shared__ float  beS[NE][DD];             // 8 KB

    const int tid  = threadIdx.x;
    const int n0   = blockIdx.x * TPB;
    const int lane = tid & 63;
    const int wid  = tid >> 6;                 // wave -> cols wid*32..+31
    const int l15  = lane & 15;
    const int quad = lane >> 4;

    for (int idx = tid; idx < TPB * DD; idx += 256) {   // stage x as bf16
        int t = idx >> 7, d = idx & 127;
        xsb[t][d] = (__bf16)x[(size_t)(n0 + t) * DD + d];
    }
    for (int idx = tid; idx < TPB * NE; idx += 256) {   // stage comb^T
        int t = idx >> 4, e = idx & 15;
        combT[e][t] = comb[(size_t)(n0 + t) * NE + e];
    }
    for (int idx = tid; idx < NE * DD; idx += 256) {    // stage be
        int e = idx >> 7, f = idx & 127;
        beS[e][f] = be[idx];
    }
    __syncthreads();

    const int nA = wid * 32;
    const int nB = nA + 16;
    f32x4 logits[4][2];
    #pragma unroll
    for (int a = 0; a < 4; a++)
        #pragma unroll
        for (int b = 0; b < 2; b++)
            logits[a][b] = (f32x4){0.f, 0.f, 0.f, 0.f};

    for (int e = 0; e < NE; e++) {
        // B fragments for this expert (in registers, reused by 4 m-tiles)
        const __bf16* bbase = WeT + (size_t)e * DD * DD;
        bf16x8 Bf[2][4];
        #pragma unroll
        for (int t2 = 0; t2 < 2; t2++) {
            const __bf16* cb = bbase + (size_t)(nA + 16 * t2 + l15) * DD + quad * 8;
            #pragma unroll
            for (int s = 0; s < 4; s++)
                Bf[t2][s] = *(const bf16x8*)(cb + 32 * s);
        }
        const float beA = beS[e][nA + l15];
        const float beB = beS[e][nB + l15];
        const f32x4 initA = {beA, beA, beA, beA};
        const f32x4 initB = {beB, beB, beB, beB};

        #pragma unroll
        for (int a = 0; a < 4; a++) {          // m-tiles: rows a*16..+15
            f32x4 acc0 = initA, acc1 = initB;
            #pragma unroll
            for (int s = 0; s < 4; s++) {
                bf16x8 Af = *(const bf16x8*)&xsb[a * 16 + l15][32 * s + quad * 8];
                acc0 = __builtin_amdgcn_mfma_f32_16x16x32_bf16(Af, Bf[0][s], acc0, 0, 0, 0);
                acc1 = __builtin_amdgcn_mfma_f32_16x16x32_bf16(Af, Bf[1][s], acc1, 0, 0, 0);
            }
            // rows quad*4+r; comb broadcast (same addr across quad lanes)
            f32x4 cv = *(const f32x4*)&combT[e][a * 16 + quad * 4];
            #pragma unroll
            for (int r = 0; r < 4; r++) {
                logits[a][0][r] = fmaf(cv[r], acc0[r], logits[a][0][r]);
                logits[a][1][r] = fmaf(cv[r], acc1[r], logits[a][1][r]);
            }
        }
    }

    // write-out: row = a*16 + quad*4 + r, cols nA+l15 / nB+l15
    #pragma unroll
    for (int a = 0; a < 4; a++) {
        #pragma unroll
        for (int r = 0; r < 4; r++) {
            size_t row = (size_t)(n0 + a * 16 + quad * 4 + r) * DD;
            out[row + nA + l15] = logits[a][0][r];
            out[row + nB + l15] = logits[a][1][r];
        }
    }
}

// ---------------------------------------------------------------------------
extern "C" void kernel_launch(void* const* d_in, const int* in_sizes, int n_in,
                              void* d_out, int out_size, void* d_ws, size_t ws_size,
                              hipStream_t stream)
{
    (void)in_sizes; (void)n_in; (void)out_size; (void)ws_size;
    const float* x     = (const float*)d_in[0];
    const float* noise = (const float*)d_in[1];
    const float* Wg    = (const float*)d_in[2];
    const float* bg    = (const float*)d_in[3];
    const float* Wn    = (const float*)d_in[4];
    const float* bn    = (const float*)d_in[5];
    const float* We    = (const float*)d_in[6];
    const float* be    = (const float*)d_in[7];
    float* out = (float*)d_out;

    char*   ws        = (char*)d_ws;
    float*  imp_block = (float*)ws;                  // 64 KB
    __bf16* WeT       = (__bf16*)(ws + 65536);       // 512 KB

    hipLaunchKernelGGL(k_prep, dim3(NE), dim3(256), 0, stream, We, WeT);
    hipLaunchKernelGGL(k_gate, dim3(NBLK), dim3(256), 0, stream,
                       x, noise, Wg, bg, Wn, bn, out, imp_block);
    hipLaunchKernelGGL(k_loss, dim3(1), dim3(256), 0, stream, imp_block, out);
    hipLaunchKernelGGL(k_expert, dim3(NBLK), dim3(256), 0, stream,
                       x, WeT, be, out + OUT_COMB, out);
}

// Round 5
// 233.461 us; speedup vs baseline: 1.3167x; 1.3167x over previous
//
#include <hip/hip_runtime.h>
#include <math.h>

// SparseMOELayer: N=65536 tokens, D=128, E=16 experts, top-3 routing.
// Outputs concat: logits[N*D] | importance_loss[1] | comb[N*E]
#define NTOK 65536
#define DD   128
#define NE   16
#define NK   3
#define TPB  64                    // tokens per block
#define NBLK (NTOK / TPB)          // 1024

#define OUT_LOSS ((size_t)NTOK * DD)
#define OUT_COMB ((size_t)NTOK * DD + 1)

typedef __bf16 bf16x8 __attribute__((ext_vector_type(8)));
typedef float  f32x4  __attribute__((ext_vector_type(4)));

__device__ __forceinline__ double softplus_d(double z) {
    return fmax(z, 0.0) + log1p(exp(-fabs(z)));
}

// ---------------------------------------------------------------------------
// K0: We[e][d][f] fp32 -> WeT[e][f][d] bf16 (B-operand layout).
// ---------------------------------------------------------------------------
__global__ __launch_bounds__(256) void k_prep(
    const float* __restrict__ We, __bf16* __restrict__ WeT)
{
    __shared__ __bf16 S[DD][DD + 8];
    const int tid = threadIdx.x;
    const int e = blockIdx.x;
    const size_t base = (size_t)e * DD * DD;
    for (int idx = tid; idx < DD * DD; idx += 256) {
        int d = idx >> 7, f = idx & 127;
        S[d][f] = (__bf16)We[base + idx];              // coalesced read
    }
    __syncthreads();
    for (int idx = tid; idx < DD * DD; idx += 256) {
        int f = idx >> 7, d = idx & 127;
        WeT[base + idx] = S[d][f];                     // coalesced write
    }
}

// ---------------------------------------------------------------------------
// K1: gating (unchanged from R3/R4 — passes, ~60-70us; next round's target).
// ---------------------------------------------------------------------------
__global__ __launch_bounds__(256, 4) void k_gate(
    const float* __restrict__ x, const float* __restrict__ noise,
    const float* __restrict__ Wg, const float* __restrict__ bg,
    const float* __restrict__ Wn, const float* __restrict__ bn,
    float* __restrict__ out, float* __restrict__ imp_block)
{
    __shared__ float  WgT[NE][DD + 4];
    __shared__ float  WnT[NE][DD + 4];
    __shared__ double gaS[TPB][NE + 1];
    __shared__ double naS[TPB][NE + 1];
    __shared__ float  tk_w[TPB][NK];
    __shared__ int    tk_e[TPB][NK];
    __shared__ float  impS[NE];

    const int tid = threadIdx.x;
    const int n0  = blockIdx.x * TPB;
    const int e   = tid & 15;
    const int tl  = tid >> 4;

    if (tid < NE) impS[tid] = 0.0f;
    for (int i = tid; i < DD * NE; i += 256) {        // transpose-load Wg/Wn
        int d = i >> 4, ee = i & 15;
        WgT[ee][d] = Wg[i];
        WnT[ee][d] = Wn[i];
    }
    __syncthreads();

    // ---- Phase 1: fp64 dots, 8 independent accumulator chains ----
    const float4* wgp = (const float4*)&WgT[e][0];
    const float4* wnp = (const float4*)&WnT[e][0];
    for (int g = 0; g < 4; g++) {
        int t = g * 16 + tl;
        const float4* xp = (const float4*)(x + (size_t)(n0 + t) * DD);
        double g0 = 0, g1 = 0, g2 = 0, g3 = 0;
        double h0 = 0, h1 = 0, h2 = 0, h3 = 0;
        #pragma unroll 4
        for (int q = 0; q < DD / 4; q++) {
            float4 xv = xp[q], wg = wgp[q], wn = wnp[q];
            g0 += (double)xv.x * wg.x; g1 += (double)xv.y * wg.y;
            g2 += (double)xv.z * wg.z; g3 += (double)xv.w * wg.w;
            h0 += (double)xv.x * wn.x; h1 += (double)xv.y * wn.y;
            h2 += (double)xv.z * wn.z; h3 += (double)xv.w * wn.w;
        }
        gaS[t][e] = (g0 + g1) + (g2 + g3);
        naS[t][e] = (h0 + h1) + (h2 + h3);
    }
    __syncthreads();

    // ---- Phase 2: gate = ga + bg + noise * softplus(na + bn) ----
    {
        const double bge = (double)bg[e], bne = (double)bn[e];
        for (int g = 0; g < 4; g++) {
            int t = g * 16 + tl;
            double nz = (double)noise[(size_t)(n0 + t) * NE + e];
            gaS[t][e] = gaS[t][e] + bge + nz * softplus_d(naS[t][e] + bne);
        }
    }
    __syncthreads();

    // ---- Phase 3: top-3 per token ----
    if (tid < TPB) {
        int t = tid;
        double v[NK]; int ix[NK];
        unsigned taken = 0;
        for (int k = 0; k < NK; k++) {
            double best = -INFINITY; int bi = 0;
            for (int j = 0; j < NE; j++) {
                if (!((taken >> j) & 1u)) {
                    double gv = gaS[t][j];
                    if (gv > best) { best = gv; bi = j; }  // strict >: low idx tie
                }
            }
            taken |= 1u << bi;
            v[k] = best; ix[k] = bi;
        }
        double e1 = exp(v[1] - v[0]);
        double e2 = exp(v[2] - v[0]);
        double inv = 1.0 / (1.0 + e1 + e2);
        tk_e[t][0] = ix[0]; tk_e[t][1] = ix[1]; tk_e[t][2] = ix[2];
        tk_w[t][0] = (float)inv;
        tk_w[t][1] = (float)(e1 * inv);
        tk_w[t][2] = (float)(e2 * inv);
    }
    __syncthreads();

    // ---- Phase 4: comb scatter + importance partials ----
    for (int g = 0; g < 4; g++) {
        int t = g * 16 + tl;
        float c = 0.f;
        if (tk_e[t][0] == e) c = tk_w[t][0];
        if (tk_e[t][1] == e) c = tk_w[t][1];
        if (tk_e[t][2] == e) c = tk_w[t][2];
        out[OUT_COMB + (size_t)(n0 + t) * NE + e] = c;
        if (c != 0.f) atomicAdd(&impS[e], c);
    }
    __syncthreads();
    if (tid < NE) imp_block[blockIdx.x * NE + tid] = impS[tid];
}

// ---------------------------------------------------------------------------
// K2: importance loss = (std(imp, ddof=1)/mean)^2.
// ---------------------------------------------------------------------------
__global__ __launch_bounds__(256) void k_loss(
    const float* __restrict__ imp_block, float* __restrict__ out)
{
    __shared__ float red[256];
    __shared__ float impv[NE];
    int tid = threadIdx.x;
    int e = tid & 15, s = tid >> 4;
    float sum = 0.f;
    for (int b = s; b < NBLK; b += 16) sum += imp_block[b * NE + e];
    red[tid] = sum;
    __syncthreads();
    if (tid < NE) {
        float t = 0.f;
        for (int q = 0; q < 16; q++) t += red[q * 16 + tid];
        impv[tid] = t;
    }
    __syncthreads();
    if (tid == 0) {
        double mean = 0.0;
        for (int i = 0; i < NE; i++) mean += (double)impv[i];
        mean /= NE;
        double var = 0.0;
        for (int i = 0; i < NE; i++) {
            double d = (double)impv[i] - mean; var += d * d;
        }
        var /= (NE - 1);
        out[OUT_LOSS] = (float)(var / (mean * mean));
    }
}

// ---------------------------------------------------------------------------
// K3: dense expert compute, memory-disciplined (R4 lesson):
//  - logits accumulate in REGISTERS across the 16-expert loop
//  - union LDS: x-tile (phase A) / yacc write-staging (phase B) -> 38 KB,
//    4 blocks/CU
//  - per-expert __syncthreads(): lockstep waves so all resident waves read
//    the same WeT slab (R3-verified L2 locality, FETCH 21 MB not 315 MB)
//  - write-out staged through LDS -> contiguous coalesced dword stores
//    (R3-verified WRITE == 32 MB, no partial-line amplification)
// MFMA 16x16x32 layouts (m89-verified):
//   A: lane l holds A[m=l&15][k=(l>>4)*8+j]; D: col=l&15, row=(l>>4)*4+reg
// ---------------------------------------------------------------------------
__global__ __launch_bounds__(256, 4) void k_expert(
    const float* __restrict__ x, const __bf16* __restrict__ WeT,
    const float* __restrict__ be, const float* __restrict__ comb,
    float* __restrict__ out)
{
    __shared__ union {
        __bf16 xsb[TPB][DD + 8];       // 17.4 KB — phase A (expert loop)
        float  yacc[TPB][DD + 4];      // 33.8 KB — phase B (write staging)
    } u;
    __shared__ float combT[NE][TPB + 4];   // 4.35 KB, [e][t]

    const int tid  = threadIdx.x;
    const int n0   = blockIdx.x * TPB;
    const int lane = tid & 63;
    const int wid  = tid >> 6;             // wave -> cols wid*32..+31
    const int l15  = lane & 15;
    const int quad = lane >> 4;

    for (int idx = tid; idx < TPB * DD; idx += 256) {   // stage x as bf16
        int t = idx >> 7, d = idx & 127;
        u.xsb[t][d] = (__bf16)x[(size_t)(n0 + t) * DD + d];
    }
    for (int idx = tid; idx < TPB * NE; idx += 256) {   // stage comb^T
        int t = idx >> 4, e = idx & 15;
        combT[e][t] = comb[(size_t)(n0 + t) * NE + e];
    }
    __syncthreads();

    const int nA = wid * 32;
    const int nB = nA + 16;
    f32x4 logits[4][2];
    #pragma unroll
    for (int a = 0; a < 4; a++)
        #pragma unroll
        for (int b = 0; b < 2; b++)
            logits[a][b] = (f32x4){0.f, 0.f, 0.f, 0.f};

    for (int e = 0; e < NE; e++) {
        // B fragments for this expert (registers, reused by 4 m-tiles)
        const __bf16* bbase = WeT + (size_t)e * DD * DD;
        bf16x8 Bf[2][4];
        #pragma unroll
        for (int t2 = 0; t2 < 2; t2++) {
            const __bf16* cb = bbase + (size_t)(nA + 16 * t2 + l15) * DD + quad * 8;
            #pragma unroll
            for (int s = 0; s < 4; s++)
                Bf[t2][s] = *(const bf16x8*)(cb + 32 * s);
        }
        const float beA = be[e * DD + nA + l15];        // L2-hot broadcast-ish
        const float beB = be[e * DD + nB + l15];
        const f32x4 initA = {beA, beA, beA, beA};
        const f32x4 initB = {beB, beB, beB, beB};

        #pragma unroll
        for (int a = 0; a < 4; a++) {          // m-tiles: rows a*16..+15
            f32x4 acc0 = initA, acc1 = initB;
            #pragma unroll
            for (int s = 0; s < 4; s++) {
                bf16x8 Af = *(const bf16x8*)&u.xsb[a * 16 + l15][32 * s + quad * 8];
                acc0 = __builtin_amdgcn_mfma_f32_16x16x32_bf16(Af, Bf[0][s], acc0, 0, 0, 0);
                acc1 = __builtin_amdgcn_mfma_f32_16x16x32_bf16(Af, Bf[1][s], acc1, 0, 0, 0);
            }
            // rows quad*4+r; comb broadcast (same addr across quad lanes)
            f32x4 cv = *(const f32x4*)&combT[e][a * 16 + quad * 4];
            #pragma unroll
            for (int r = 0; r < 4; r++) {
                logits[a][0][r] = fmaf(cv[r], acc0[r], logits[a][0][r]);
                logits[a][1][r] = fmaf(cv[r], acc1[r], logits[a][1][r]);
            }
        }
        __syncthreads();   // lockstep waves: shared WeT slab stays L1/L2-hot
    }

    // phase B: registers -> LDS (xsb is dead; barrier above protects reuse)
    #pragma unroll
    for (int a = 0; a < 4; a++) {
        #pragma unroll
        for (int r = 0; r < 4; r++) {
            int row = a * 16 + quad * 4 + r;
            u.yacc[row][nA + l15] = logits[a][0][r];
            u.yacc[row][nB + l15] = logits[a][1][r];
        }
    }
    __syncthreads();

    float* op = out + (size_t)n0 * DD;
    for (int idx = tid; idx < TPB * DD; idx += 256) {   // coalesced store
        int t = idx >> 7, f = idx & 127;
        op[idx] = u.yacc[t][f];
    }
}

// ---------------------------------------------------------------------------
extern "C" void kernel_launch(void* const* d_in, const int* in_sizes, int n_in,
                              void* d_out, int out_size, void* d_ws, size_t ws_size,
                              hipStream_t stream)
{
    (void)in_sizes; (void)n_in; (void)out_size; (void)ws_size;
    const float* x     = (const float*)d_in[0];
    const float* noise = (const float*)d_in[1];
    const float* Wg    = (const float*)d_in[2];
    const float* bg    = (const float*)d_in[3];
    const float* Wn    = (const float*)d_in[4];
    const float* bn    = (const float*)d_in[5];
    const float* We    = (const float*)d_in[6];
    const float* be    = (const float*)d_in[7];
    float* out = (float*)d_out;

    char*   ws        = (char*)d_ws;
    float*  imp_block = (float*)ws;                  // 64 KB
    __bf16* WeT       = (__bf16*)(ws + 65536);       // 512 KB

    hipLaunchKernelGGL(k_prep, dim3(NE), dim3(256), 0, stream, We, WeT);
    hipLaunchKernelGGL(k_gate, dim3(NBLK), dim3(256), 0, stream,
                       x, noise, Wg, bg, Wn, bn, out, imp_block);
    hipLaunchKernelGGL(k_loss, dim3(1), dim3(256), 0, stream, imp_block, out);
    hipLaunchKernelGGL(k_expert, dim3(NBLK), dim3(256), 0, stream,
                       x, WeT, be, out + OUT_COMB, out);
}

// Round 6
// 218.592 us; speedup vs baseline: 1.4063x; 1.0680x over previous
//
#include <hip/hip_runtime.h>
#include <math.h>

// SparseMOELayer: N=65536 tokens, D=128, E=16 experts, top-3 routing.
// Outputs concat: logits[N*D] | importance_loss[1] | comb[N*E]
#define NTOK 65536
#define DD   128
#define NE   16
#define NK   3
#define TPB  64                    // tokens per block
#define NBLK (NTOK / TPB)          // 1024

#define OUT_LOSS ((size_t)NTOK * DD)
#define OUT_COMB ((size_t)NTOK * DD + 1)

typedef __bf16 bf16x8 __attribute__((ext_vector_type(8)));
typedef float  f32x4  __attribute__((ext_vector_type(4)));

__device__ __forceinline__ double softplus_d(double z) {
    return fmax(z, 0.0) + log1p(exp(-fabs(z)));
}

// ---------------------------------------------------------------------------
// K0: We[e][d][f] fp32 -> WeT[e][f][d] bf16 (B-operand layout).
// ---------------------------------------------------------------------------
__global__ __launch_bounds__(256) void k_prep(
    const float* __restrict__ We, __bf16* __restrict__ WeT)
{
    __shared__ __bf16 S[DD][DD + 8];
    const int tid = threadIdx.x;
    const int e = blockIdx.x;
    const size_t base = (size_t)e * DD * DD;
    for (int idx = tid; idx < DD * DD; idx += 256) {
        int d = idx >> 7, f = idx & 127;
        S[d][f] = (__bf16)We[base + idx];              // coalesced read
    }
    __syncthreads();
    for (int idx = tid; idx < DD * DD; idx += 256) {
        int f = idx >> 7, d = idx & 127;
        WeT[base + idx] = S[d][f];                     // coalesced write
    }
}

// ---------------------------------------------------------------------------
// K1: gating (unchanged — next round's target).
// ---------------------------------------------------------------------------
__global__ __launch_bounds__(256, 4) void k_gate(
    const float* __restrict__ x, const float* __restrict__ noise,
    const float* __restrict__ Wg, const float* __restrict__ bg,
    const float* __restrict__ Wn, const float* __restrict__ bn,
    float* __restrict__ out, float* __restrict__ imp_block)
{
    __shared__ float  WgT[NE][DD + 4];
    __shared__ float  WnT[NE][DD + 4];
    __shared__ double gaS[TPB][NE + 1];
    __shared__ double naS[TPB][NE + 1];
    __shared__ float  tk_w[TPB][NK];
    __shared__ int    tk_e[TPB][NK];
    __shared__ float  impS[NE];

    const int tid = threadIdx.x;
    const int n0  = blockIdx.x * TPB;
    const int e   = tid & 15;
    const int tl  = tid >> 4;

    if (tid < NE) impS[tid] = 0.0f;
    for (int i = tid; i < DD * NE; i += 256) {        // transpose-load Wg/Wn
        int d = i >> 4, ee = i & 15;
        WgT[ee][d] = Wg[i];
        WnT[ee][d] = Wn[i];
    }
    __syncthreads();

    // ---- Phase 1: fp64 dots, 8 independent accumulator chains ----
    const float4* wgp = (const float4*)&WgT[e][0];
    const float4* wnp = (const float4*)&WnT[e][0];
    for (int g = 0; g < 4; g++) {
        int t = g * 16 + tl;
        const float4* xp = (const float4*)(x + (size_t)(n0 + t) * DD);
        double g0 = 0, g1 = 0, g2 = 0, g3 = 0;
        double h0 = 0, h1 = 0, h2 = 0, h3 = 0;
        #pragma unroll 4
        for (int q = 0; q < DD / 4; q++) {
            float4 xv = xp[q], wg = wgp[q], wn = wnp[q];
            g0 += (double)xv.x * wg.x; g1 += (double)xv.y * wg.y;
            g2 += (double)xv.z * wg.z; g3 += (double)xv.w * wg.w;
            h0 += (double)xv.x * wn.x; h1 += (double)xv.y * wn.y;
            h2 += (double)xv.z * wn.z; h3 += (double)xv.w * wn.w;
        }
        gaS[t][e] = (g0 + g1) + (g2 + g3);
        naS[t][e] = (h0 + h1) + (h2 + h3);
    }
    __syncthreads();

    // ---- Phase 2: gate = ga + bg + noise * softplus(na + bn) ----
    {
        const double bge = (double)bg[e], bne = (double)bn[e];
        for (int g = 0; g < 4; g++) {
            int t = g * 16 + tl;
            double nz = (double)noise[(size_t)(n0 + t) * NE + e];
            gaS[t][e] = gaS[t][e] + bge + nz * softplus_d(naS[t][e] + bne);
        }
    }
    __syncthreads();

    // ---- Phase 3: top-3 per token ----
    if (tid < TPB) {
        int t = tid;
        double v[NK]; int ix[NK];
        unsigned taken = 0;
        for (int k = 0; k < NK; k++) {
            double best = -INFINITY; int bi = 0;
            for (int j = 0; j < NE; j++) {
                if (!((taken >> j) & 1u)) {
                    double gv = gaS[t][j];
                    if (gv > best) { best = gv; bi = j; }  // strict >: low idx tie
                }
            }
            taken |= 1u << bi;
            v[k] = best; ix[k] = bi;
        }
        double e1 = exp(v[1] - v[0]);
        double e2 = exp(v[2] - v[0]);
        double inv = 1.0 / (1.0 + e1 + e2);
        tk_e[t][0] = ix[0]; tk_e[t][1] = ix[1]; tk_e[t][2] = ix[2];
        tk_w[t][0] = (float)inv;
        tk_w[t][1] = (float)(e1 * inv);
        tk_w[t][2] = (float)(e2 * inv);
    }
    __syncthreads();

    // ---- Phase 4: comb scatter + importance partials ----
    for (int g = 0; g < 4; g++) {
        int t = g * 16 + tl;
        float c = 0.f;
        if (tk_e[t][0] == e) c = tk_w[t][0];
        if (tk_e[t][1] == e) c = tk_w[t][1];
        if (tk_e[t][2] == e) c = tk_w[t][2];
        out[OUT_COMB + (size_t)(n0 + t) * NE + e] = c;
        if (c != 0.f) atomicAdd(&impS[e], c);
    }
    __syncthreads();
    if (tid < NE) imp_block[blockIdx.x * NE + tid] = impS[tid];
}

// ---------------------------------------------------------------------------
// K2: importance loss = (std(imp, ddof=1)/mean)^2.
// ---------------------------------------------------------------------------
__global__ __launch_bounds__(256) void k_loss(
    const float* __restrict__ imp_block, float* __restrict__ out)
{
    __shared__ float red[256];
    __shared__ float impv[NE];
    int tid = threadIdx.x;
    int e = tid & 15, s = tid >> 4;
    float sum = 0.f;
    for (int b = s; b < NBLK; b += 16) sum += imp_block[b * NE + e];
    red[tid] = sum;
    __syncthreads();
    if (tid < NE) {
        float t = 0.f;
        for (int q = 0; q < 16; q++) t += red[q * 16 + tid];
        impv[tid] = t;
    }
    __syncthreads();
    if (tid == 0) {
        double mean = 0.0;
        for (int i = 0; i < NE; i++) mean += (double)impv[i];
        mean /= NE;
        double var = 0.0;
        for (int i = 0; i < NE; i++) {
            double d = (double)impv[i] - mean; var += d * d;
        }
        var /= (NE - 1);
        out[OUT_LOSS] = (float)(var / (mean * mean));
    }
}

// ---------------------------------------------------------------------------
// Load one expert's B fragments (2 n-tiles x 4 k-steps) into registers.
// ---------------------------------------------------------------------------
__device__ __forceinline__ void loadB(
    bf16x8 (&dst)[2][4], const __bf16* __restrict__ WeT,
    int e, int nA, int l15, int quad)
{
    const __bf16* bbase = WeT + (size_t)e * DD * DD;
    #pragma unroll
    for (int t2 = 0; t2 < 2; t2++) {
        const __bf16* cb = bbase + (size_t)(nA + 16 * t2 + l15) * DD + quad * 8;
        #pragma unroll
        for (int s = 0; s < 4; s++)
            dst[t2][s] = *(const bf16x8*)(cb + 32 * s);
    }
}

// ---------------------------------------------------------------------------
// K3: dense expert compute, register-resident (R5 lesson: 25.2M LDS bank
// conflicts came from re-reading A-frags from LDS 16x per block + per-expert
// barriers serializing L2 latency):
//  - A-frags hoisted to registers ONCE (reused 32x) -> near-zero in-loop LDS
//  - B-frags double-buffered in registers, prefetch e+1 during e's MFMAs
//    (WeT = 512 KB, L2-resident per XCD; no barrier needed for locality)
//  - NO barriers in expert loop; 8 independent acc chains (s-outer a-inner)
//  - bias applied in epilogue: logits += sum_e combT[e][row]*beS[e][col]
//  - write-out staged through union LDS -> coalesced stores (R5-verified
//    WRITE=32MB)
// MFMA 16x16x32 layouts (m89-verified):
//   A: lane l holds A[m=l&15][k=(l>>4)*8+j]; D: col=l&15, row=(l>>4)*4+reg
// ---------------------------------------------------------------------------
__global__ __launch_bounds__(256, 2) void k_expert(
    const float* __restrict__ x, const __bf16* __restrict__ WeT,
    const float* __restrict__ be, const float* __restrict__ comb,
    float* __restrict__ out)
{
    __shared__ union {
        __bf16 xsb[TPB][DD + 8];       // 17.4 KB — phase A (A-frag source)
        float  yacc[TPB][DD + 4];      // 33.8 KB — phase B (write staging)
    } u;
    __shared__ float combT[NE][TPB + 4];   // 4.35 KB, [e][t]
    __shared__ float beS[NE][DD];          // 8 KB

    const int tid  = threadIdx.x;
    const int n0   = blockIdx.x * TPB;
    const int lane = tid & 63;
    const int wid  = tid >> 6;             // wave -> cols wid*32..+31
    const int l15  = lane & 15;
    const int quad = lane >> 4;

    for (int idx = tid; idx < TPB * DD; idx += 256) {   // stage x as bf16
        int t = idx >> 7, d = idx & 127;
        u.xsb[t][d] = (__bf16)x[(size_t)(n0 + t) * DD + d];
    }
    for (int idx = tid; idx < TPB * NE; idx += 256) {   // stage comb^T
        int t = idx >> 4, e = idx & 15;
        combT[e][t] = comb[(size_t)(n0 + t) * NE + e];
    }
    for (int idx = tid; idx < NE * DD; idx += 256) {    // stage be
        int e = idx >> 7, f = idx & 127;
        beS[e][f] = be[idx];
    }
    __syncthreads();

    const int nA = wid * 32;
    const int nB = nA + 16;

    // hoist A fragments: Af[a][s] independent of expert -> read LDS once
    bf16x8 Af[4][4];
    #pragma unroll
    for (int a = 0; a < 4; a++)
        #pragma unroll
        for (int s = 0; s < 4; s++)
            Af[a][s] = *(const bf16x8*)&u.xsb[a * 16 + l15][32 * s + quad * 8];
    __syncthreads();   // xsb dead everywhere after this -> safe yacc reuse

    f32x4 logits[4][2];
    #pragma unroll
    for (int a = 0; a < 4; a++) {
        logits[a][0] = (f32x4){0.f, 0.f, 0.f, 0.f};
        logits[a][1] = (f32x4){0.f, 0.f, 0.f, 0.f};
    }

    bf16x8 Bf[2][2][4];                    // double buffer
    loadB(Bf[0], WeT, 0, nA, l15, quad);

    #pragma unroll 2
    for (int e = 0; e < NE; e++) {
        const int cur = e & 1;
        if (e + 1 < NE) loadB(Bf[cur ^ 1], WeT, e + 1, nA, l15, quad);

        f32x4 acc[4][2];
        #pragma unroll
        for (int a = 0; a < 4; a++) {
            acc[a][0] = (f32x4){0.f, 0.f, 0.f, 0.f};
            acc[a][1] = (f32x4){0.f, 0.f, 0.f, 0.f};
        }
        #pragma unroll
        for (int s = 0; s < 4; s++)        // s-outer: 8 indep chains, gap 8
            #pragma unroll
            for (int a = 0; a < 4; a++) {
                acc[a][0] = __builtin_amdgcn_mfma_f32_16x16x32_bf16(
                    Af[a][s], Bf[cur][0][s], acc[a][0], 0, 0, 0);
                acc[a][1] = __builtin_amdgcn_mfma_f32_16x16x32_bf16(
                    Af[a][s], Bf[cur][1][s], acc[a][1], 0, 0, 0);
            }
        #pragma unroll
        for (int a = 0; a < 4; a++) {
            f32x4 cv = *(const f32x4*)&combT[e][a * 16 + quad * 4]; // broadcast
            #pragma unroll
            for (int r = 0; r < 4; r++) {
                logits[a][0][r] = fmaf(cv[r], acc[a][0][r], logits[a][0][r]);
                logits[a][1][r] = fmaf(cv[r], acc[a][1][r], logits[a][1][r]);
            }
        }
    }

    // epilogue bias: logits[row][col] += sum_e combT[e][row] * beS[e][col]
    #pragma unroll 4
    for (int e = 0; e < NE; e++) {
        float bA = beS[e][nA + l15];       // stride-1 across lanes
        float bB = beS[e][nB + l15];
        #pragma unroll
        for (int a = 0; a < 4; a++) {
            f32x4 cv = *(const f32x4*)&combT[e][a * 16 + quad * 4];
            #pragma unroll
            for (int r = 0; r < 4; r++) {
                logits[a][0][r] = fmaf(cv[r], bA, logits[a][0][r]);
                logits[a][1][r] = fmaf(cv[r], bB, logits[a][1][r]);
            }
        }
    }

    // registers -> LDS -> coalesced contiguous stores
    #pragma unroll
    for (int a = 0; a < 4; a++) {
        #pragma unroll
        for (int r = 0; r < 4; r++) {
            int row = a * 16 + quad * 4 + r;
            u.yacc[row][nA + l15] = logits[a][0][r];
            u.yacc[row][nB + l15] = logits[a][1][r];
        }
    }
    __syncthreads();

    float* op = out + (size_t)n0 * DD;
    for (int idx = tid; idx < TPB * DD; idx += 256) {
        int t = idx >> 7, f = idx & 127;
        op[idx] = u.yacc[t][f];
    }
}

// ---------------------------------------------------------------------------
extern "C" void kernel_launch(void* const* d_in, const int* in_sizes, int n_in,
                              void* d_out, int out_size, void* d_ws, size_t ws_size,
                              hipStream_t stream)
{
    (void)in_sizes; (void)n_in; (void)out_size; (void)ws_size;
    const float* x     = (const float*)d_in[0];
    const float* noise = (const float*)d_in[1];
    const float* Wg    = (const float*)d_in[2];
    const float* bg    = (const float*)d_in[3];
    const float* Wn    = (const float*)d_in[4];
    const float* bn    = (const float*)d_in[5];
    const float* We    = (const float*)d_in[6];
    const float* be    = (const float*)d_in[7];
    float* out = (float*)d_out;

    char*   ws        = (char*)d_ws;
    float*  imp_block = (float*)ws;                  // 64 KB
    __bf16* WeT       = (__bf16*)(ws + 65536);       // 512 KB

    hipLaunchKernelGGL(k_prep, dim3(NE), dim3(256), 0, stream, We, WeT);
    hipLaunchKernelGGL(k_gate, dim3(NBLK), dim3(256), 0, stream,
                       x, noise, Wg, bg, Wn, bn, out, imp_block);
    hipLaunchKernelGGL(k_loss, dim3(1), dim3(256), 0, stream, imp_block, out);
    hipLaunchKernelGGL(k_expert, dim3(NBLK), dim3(256), 0, stream,
                       x, WeT, be, out + OUT_COMB, out);
}

// Round 7
// 172.894 us; speedup vs baseline: 1.7780x; 1.2643x over previous
//
#include <hip/hip_runtime.h>
#include <math.h>

// SparseMOELayer: N=65536 tokens, D=128, E=16 experts, top-3 routing.
// Outputs concat: logits[N*D] | importance_loss[1] | comb[N*E]
#define NTOK 65536
#define DD   128
#define NE   16
#define NK   3
#define TPB  64                    // tokens per block
#define NBLK (NTOK / TPB)          // 1024

#define OUT_LOSS ((size_t)NTOK * DD)
#define OUT_COMB ((size_t)NTOK * DD + 1)

typedef __bf16 bf16x8 __attribute__((ext_vector_type(8)));
typedef float  f32x4  __attribute__((ext_vector_type(4)));

__device__ __forceinline__ double softplus_d(double z) {
    return fmax(z, 0.0) + log1p(exp(-fabs(z)));
}

// ---------------------------------------------------------------------------
// K0: pack We[e][d][f] fp32 -> WeTp bf16, FRAGMENT-MAJOR:
//   WeTp[e][nt][s][lane][j]  (flat: e*16384 + (nt*4+s)*512 + lane*8 + j)
//   holds We[d = s*32 + (lane>>4)*8 + j][f = nt*16 + (lane&15)].
// Consumer loadBp then reads one bf16x8/lane at consecutive 16B -> each
// B-frag load is ONE coalesced 1KB transaction (R6's loadB gathered 16
// 256B-strided rows per instruction -> TA line-serialization).
// 64 blocks: (expert e = blk>>2, k-step s = blk&3). Block 0 zeroes imp_g.
// ---------------------------------------------------------------------------
__global__ __launch_bounds__(256) void k_prep(
    const float* __restrict__ We, __bf16* __restrict__ WeTp,
    float* __restrict__ imp_g)
{
    __shared__ __bf16 S[32][DD + 8];
    const int tid = threadIdx.x;
    const int e  = blockIdx.x >> 2;
    const int qd = blockIdx.x & 3;             // == k-step s
    if (blockIdx.x == 0 && tid < NE) imp_g[tid] = 0.f;
    const size_t base = (size_t)e * DD * DD + (size_t)qd * 32 * DD;
    for (int i = tid; i < 32 * DD; i += 256) { // coalesced read, d-quarter
        int dd = i >> 7, f = i & 127;
        S[dd][f] = (__bf16)We[base + i];
    }
    __syncthreads();
    #pragma unroll
    for (int it = 0; it < 2; it++) {
        int lin  = it * 256 + tid;             // 0..511 vectors
        int nt   = lin >> 6;
        int lane = lin & 63;
        int quad = lane >> 4, l15 = lane & 15;
        int f = nt * 16 + l15;
        bf16x8 vv;
        #pragma unroll
        for (int j = 0; j < 8; j++) vv[j] = S[quad * 8 + j][f];
        *(bf16x8*)(WeTp + (size_t)e * 16384 +
                   ((size_t)(nt * 4 + qd) * 64 + lane) * 8) = vv;   // coalesced
    }
}

// ---------------------------------------------------------------------------
// Load one expert's B fragments (2 n-tiles x 4 k-steps) from packed WeTp.
// Each load: lane-consecutive 16B -> one 1KB coalesced transaction.
// ---------------------------------------------------------------------------
__device__ __forceinline__ void loadBp(
    bf16x8 (&dst)[2][4], const __bf16* __restrict__ WeTp,
    int e, int wid, int lane)
{
    const __bf16* b = WeTp + (size_t)e * 16384 + (size_t)lane * 8;
    #pragma unroll
    for (int t2 = 0; t2 < 2; t2++)
        #pragma unroll
        for (int s = 0; s < 4; s++)
            dst[t2][s] = *(const bf16x8*)(b + ((wid * 2 + t2) * 4 + s) * 512);
}

// ---------------------------------------------------------------------------
// K1: FUSED gate + expert. 64 tokens/block.
// Gate phases (fp64, R3-verified numerics) -> top-3 -> comb (LDS-direct +
// global write) -> dense MFMA expert loop (R6 register-resident structure,
// packed-coalesced B) -> bias epilogue -> coalesced store.
// Importance: LDS partials -> one global atomicAdd per expert per block
// (imp_g zeroed by k_prep, stream-ordered).
// LDS unions (52.3 KB total -> 3 blocks/CU if VGPR allows):
//   union u: gate fp64 scratch (17.4K) | xsb bf16 (17.4K) | yacc f32 (33.8K)
//   union v: WgT+WnT (16.9K, dead after dot phase) | beS+combT (12.5K)
// MFMA 16x16x32 layouts (m89-verified):
//   A: lane l holds A[m=l&15][k=(l>>4)*8+j]; D: col=l&15, row=(l>>4)*4+reg
// ---------------------------------------------------------------------------
__global__ __launch_bounds__(256, 2) void k_fused(
    const float* __restrict__ x, const float* __restrict__ noise,
    const float* __restrict__ Wg, const float* __restrict__ bg,
    const float* __restrict__ Wn, const float* __restrict__ bn,
    const __bf16* __restrict__ WeTp, const float* __restrict__ be,
    float* __restrict__ out, float* __restrict__ imp_g)
{
    __shared__ union {
        struct { double ga[TPB][NE + 1]; double na[TPB][NE + 1]; } g;  // 17.4K
        __bf16 xsb[TPB][DD + 8];                                       // 17.4K
        float  yacc[TPB][DD + 4];                                      // 33.8K
    } u;
    __shared__ union {
        struct { float WgT[NE][DD + 4]; float WnT[NE][DD + 4]; } w;    // 16.9K
        struct { float beS[NE][DD]; float combT[NE][TPB + 4]; } p;     // 12.5K
    } v;
    __shared__ float tkw[TPB][NK];
    __shared__ int   tke[TPB][NK];
    __shared__ float impS[NE];

    const int tid  = threadIdx.x;
    const int n0   = blockIdx.x * TPB;
    const int lane = tid & 63;
    const int wid  = tid >> 6;             // wave -> cols wid*32..+31
    const int l15  = lane & 15;
    const int quad = lane >> 4;
    const int e16  = tid & 15;             // gate-phase expert id
    const int tl   = tid >> 4;             // gate-phase token lane

    // ---- G1: stage transposed gate weights; zero impS ----
    if (tid < NE) impS[tid] = 0.0f;
    for (int i = tid; i < DD * NE; i += 256) {
        int d = i >> 4, ee = i & 15;
        v.w.WgT[ee][d] = Wg[i];
        v.w.WnT[ee][d] = Wn[i];
    }
    __syncthreads();

    // ---- G2: fp64 dots (8 indep chains); x via 16-lane broadcast float4 ----
    {
        const float4* wgp = (const float4*)&v.w.WgT[e16][0];
        const float4* wnp = (const float4*)&v.w.WnT[e16][0];
        for (int g = 0; g < 4; g++) {
            int t = g * 16 + tl;
            const float4* xp = (const float4*)(x + (size_t)(n0 + t) * DD);
            double g0 = 0, g1 = 0, g2 = 0, g3 = 0;
            double h0 = 0, h1 = 0, h2 = 0, h3 = 0;
            #pragma unroll 4
            for (int q = 0; q < DD / 4; q++) {
                float4 xv = xp[q], wg = wgp[q], wn = wnp[q];
                g0 += (double)xv.x * wg.x; g1 += (double)xv.y * wg.y;
                g2 += (double)xv.z * wg.z; g3 += (double)xv.w * wg.w;
                h0 += (double)xv.x * wn.x; h1 += (double)xv.y * wn.y;
                h2 += (double)xv.z * wn.z; h3 += (double)xv.w * wn.w;
            }
            u.g.ga[t][e16] = (g0 + g1) + (g2 + g3);
            u.g.na[t][e16] = (h0 + h1) + (h2 + h3);
        }
    }
    __syncthreads();

    // ---- G3: gate = ga + bg + noise * softplus(na + bn) ----
    {
        const double bge = (double)bg[e16], bne = (double)bn[e16];
        for (int g = 0; g < 4; g++) {
            int t = g * 16 + tl;
            double nz = (double)noise[(size_t)(n0 + t) * NE + e16];
            u.g.ga[t][e16] = u.g.ga[t][e16] + bge
                           + nz * softplus_d(u.g.na[t][e16] + bne);
        }
    }
    __syncthreads();

    // ---- G4: top-3 + softmax (64 threads) ----
    if (tid < TPB) {
        int t = tid;
        double vk[NK]; int ix[NK];
        unsigned taken = 0;
        for (int k = 0; k < NK; k++) {
            double best = -INFINITY; int bi = 0;
            for (int j = 0; j < NE; j++) {
                if (!((taken >> j) & 1u)) {
                    double gv = u.g.ga[t][j];
                    if (gv > best) { best = gv; bi = j; }  // strict >: low idx tie
                }
            }
            taken |= 1u << bi;
            vk[k] = best; ix[k] = bi;
        }
        double e1 = exp(vk[1] - vk[0]);
        double e2 = exp(vk[2] - vk[0]);
        double inv = 1.0 / (1.0 + e1 + e2);
        tke[t][0] = ix[0]; tke[t][1] = ix[1]; tke[t][2] = ix[2];
        tkw[t][0] = (float)inv;
        tkw[t][1] = (float)(e1 * inv);
        tkw[t][2] = (float)(e2 * inv);
    }
    __syncthreads();   // gate scratch (u.g) dead; v.w dead -> stage new data

    // ---- G5/X1: comb (global + LDS combT), impS, beS, xsb staging ----
    for (int g = 0; g < 4; g++) {
        int t = g * 16 + tl;
        float c = 0.f;
        if (tke[t][0] == e16) c = tkw[t][0];
        if (tke[t][1] == e16) c = tkw[t][1];
        if (tke[t][2] == e16) c = tkw[t][2];
        out[OUT_COMB + (size_t)(n0 + t) * NE + e16] = c;
        v.p.combT[e16][t] = c;
        if (c != 0.f) atomicAdd(&impS[e16], c);
    }
    for (int idx = tid; idx < NE * DD; idx += 256)      // stage be
        v.p.beS[idx >> 7][idx & 127] = be[idx];
    for (int idx = tid; idx < TPB * DD; idx += 256) {   // stage x as bf16
        int t = idx >> 7, d = idx & 127;
        u.xsb[t][d] = (__bf16)x[(size_t)(n0 + t) * DD + d];
    }
    __syncthreads();

    // importance partials -> global (device-scope atomics)
    if (tid < NE) atomicAdd(&imp_g[tid], impS[tid]);

    // ---- X2: hoist A fragments (expert-independent, read LDS once) ----
    bf16x8 Af[4][4];
    #pragma unroll
    for (int a = 0; a < 4; a++)
        #pragma unroll
        for (int s = 0; s < 4; s++)
            Af[a][s] = *(const bf16x8*)&u.xsb[a * 16 + l15][32 * s + quad * 8];
    __syncthreads();   // xsb dead -> u.yacc reusable

    // ---- X3: expert loop, register-resident, dbuf coalesced B ----
    f32x4 logits[4][2];
    #pragma unroll
    for (int a = 0; a < 4; a++) {
        logits[a][0] = (f32x4){0.f, 0.f, 0.f, 0.f};
        logits[a][1] = (f32x4){0.f, 0.f, 0.f, 0.f};
    }
    bf16x8 Bf[2][2][4];
    loadBp(Bf[0], WeTp, 0, wid, lane);

    #pragma unroll 2
    for (int e = 0; e < NE; e++) {
        const int cur = e & 1;
        if (e + 1 < NE) loadBp(Bf[cur ^ 1], WeTp, e + 1, wid, lane);

        f32x4 acc[4][2];
        #pragma unroll
        for (int a = 0; a < 4; a++) {
            acc[a][0] = (f32x4){0.f, 0.f, 0.f, 0.f};
            acc[a][1] = (f32x4){0.f, 0.f, 0.f, 0.f};
        }
        #pragma unroll
        for (int s = 0; s < 4; s++)        // s-outer: 8 indep chains
            #pragma unroll
            for (int a = 0; a < 4; a++) {
                acc[a][0] = __builtin_amdgcn_mfma_f32_16x16x32_bf16(
                    Af[a][s], Bf[cur][0][s], acc[a][0], 0, 0, 0);
                acc[a][1] = __builtin_amdgcn_mfma_f32_16x16x32_bf16(
                    Af[a][s], Bf[cur][1][s], acc[a][1], 0, 0, 0);
            }
        #pragma unroll
        for (int a = 0; a < 4; a++) {
            f32x4 cv = *(const f32x4*)&v.p.combT[e][a * 16 + quad * 4];
            #pragma unroll
            for (int r = 0; r < 4; r++) {
                logits[a][0][r] = fmaf(cv[r], acc[a][0][r], logits[a][0][r]);
                logits[a][1][r] = fmaf(cv[r], acc[a][1][r], logits[a][1][r]);
            }
        }
    }

    // ---- X4: bias epilogue + LDS-staged coalesced store ----
    const int nA = wid * 32, nB = nA + 16;
    #pragma unroll 4
    for (int e = 0; e < NE; e++) {
        float bA = v.p.beS[e][nA + l15];
        float bB = v.p.beS[e][nB + l15];
        #pragma unroll
        for (int a = 0; a < 4; a++) {
            f32x4 cv = *(const f32x4*)&v.p.combT[e][a * 16 + quad * 4];
            #pragma unroll
            for (int r = 0; r < 4; r++) {
                logits[a][0][r] = fmaf(cv[r], bA, logits[a][0][r]);
                logits[a][1][r] = fmaf(cv[r], bB, logits[a][1][r]);
            }
        }
    }
    #pragma unroll
    for (int a = 0; a < 4; a++) {
        #pragma unroll
        for (int r = 0; r < 4; r++) {
            int row = a * 16 + quad * 4 + r;
            u.yacc[row][nA + l15] = logits[a][0][r];
            u.yacc[row][nB + l15] = logits[a][1][r];
        }
    }
    __syncthreads();
    float* op = out + (size_t)n0 * DD;
    for (int idx = tid; idx < TPB * DD; idx += 256) {
        int t = idx >> 7, f = idx & 127;
        op[idx] = u.yacc[t][f];
    }
}

// ---------------------------------------------------------------------------
// K2: loss from 16 globally-accumulated importances (atomic sums from k_fused).
// ---------------------------------------------------------------------------
__global__ __launch_bounds__(64) void k_loss(
    const float* __restrict__ imp_g, float* __restrict__ out)
{
    if (threadIdx.x == 0) {
        double mean = 0.0;
        for (int i = 0; i < NE; i++) mean += (double)imp_g[i];
        mean /= NE;
        double var = 0.0;
        for (int i = 0; i < NE; i++) {
            double d = (double)imp_g[i] - mean; var += d * d;
        }
        var /= (NE - 1);                    // ddof=1
        out[OUT_LOSS] = (float)(var / (mean * mean));
    }
}

// ---------------------------------------------------------------------------
extern "C" void kernel_launch(void* const* d_in, const int* in_sizes, int n_in,
                              void* d_out, int out_size, void* d_ws, size_t ws_size,
                              hipStream_t stream)
{
    (void)in_sizes; (void)n_in; (void)out_size; (void)ws_size;
    const float* x     = (const float*)d_in[0];
    const float* noise = (const float*)d_in[1];
    const float* Wg    = (const float*)d_in[2];
    const float* bg    = (const float*)d_in[3];
    const float* Wn    = (const float*)d_in[4];
    const float* bn    = (const float*)d_in[5];
    const float* We    = (const float*)d_in[6];
    const float* be    = (const float*)d_in[7];
    float* out = (float*)d_out;

    char*   ws    = (char*)d_ws;
    float*  imp_g = (float*)ws;                  // 64 B (16 floats)
    __bf16* WeTp  = (__bf16*)(ws + 1024);        // 512 KB, 16B-aligned

    hipLaunchKernelGGL(k_prep, dim3(64), dim3(256), 0, stream,
                       We, WeTp, imp_g);
    hipLaunchKernelGGL(k_fused, dim3(NBLK), dim3(256), 0, stream,
                       x, noise, Wg, bg, Wn, bn, WeTp, be, out, imp_g);
    hipLaunchKernelGGL(k_loss, dim3(1), dim3(64), 0, stream, imp_g, out);
}